// Round 6
// baseline (155.148 us; speedup 1.0000x reference)
//
#include <hip/hip_runtime.h>
#include <math.h>

#define DIM 64
#define NNB 16
#define BATCH 16384

typedef float4 f4;

__device__ __forceinline__ float dot4(const f4 a, const f4 b) {
    return fmaf(a.x, b.x, fmaf(a.y, b.y, fmaf(a.z, b.z, a.w * b.w)));
}

// Sum across the 4 lane-groups (lanes differing in bits 4,5); chunk stays put.
__device__ __forceinline__ f4 xgrp_sum(f4 v) {
    v.x += __shfl_xor(v.x, 16, 64); v.y += __shfl_xor(v.y, 16, 64);
    v.z += __shfl_xor(v.z, 16, 64); v.w += __shfl_xor(v.w, 16, 64);
    v.x += __shfl_xor(v.x, 32, 64); v.y += __shfl_xor(v.y, 32, 64);
    v.z += __shfl_xor(v.z, 32, 64); v.w += __shfl_xor(v.w, 32, 64);
    return v;
}

template <int WPB>
__global__ __launch_bounds__(WPB * 64, 4) void klgcn_kernel(
    const int* __restrict__ u, const int* __restrict__ v,
    const int* __restrict__ user_neighbor, const int* __restrict__ item_neighbor,
    const int* __restrict__ adj_ent, const int* __restrict__ adj_rel,
    const float* __restrict__ usr_emb, const float* __restrict__ ent_emb,
    const float* __restrict__ rel_emb, const float* __restrict__ agg_W,
    const float* __restrict__ agg_b, float* __restrict__ out)
{
    const int wave = threadIdx.x >> 6;
    const int lane = threadIdx.x & 63;
    const int g = lane >> 4;   // group 0..3: owns neighbor rows 4g..4g+3
    const int s = lane & 15;   // chunk 0..15: dims [4s, 4s+4)
    const int b = __builtin_amdgcn_readfirstlane(blockIdx.x * WPB + wave);

    const f4* __restrict__ usr4 = (const f4*)usr_emb;
    const f4* __restrict__ ent4 = (const f4*)ent_emb;
    const f4* __restrict__ rel4 = (const f4*)rel_emb;
    const f4* __restrict__ W4   = (const f4*)agg_W;
    const f4* __restrict__ b4p  = (const f4*)agg_b;
    const int4* __restrict__ it4 = (const int4*)item_neighbor;
    const int4* __restrict__ un4 = (const int4*)user_neighbor;
    const int4* __restrict__ ar4 = (const int4*)adj_rel;
    const int4* __restrict__ ae4 = (const int4*)adj_ent;

    const int ub = __builtin_amdgcn_readfirstlane(u[b]);
    const int vb = __builtin_amdgcn_readfirstlane(v[b]);

    // ---- Index loads (one int4 per table; lane-contiguous, no scratch).
    const int4 iit = it4[b * 4 + g];          // item_neighbor rows 4g..4g+3
    const int4 iun = un4[b * 4 + g];          // user_neighbor rows 4g..4g+3
    const int4 iar = ar4[vb * 4 + g];         // adj_rel rows 4g..4g+3
    const int4 iae = ae4[vb * 4 + g];         // adj_ent rows 4g..4g+3

    // ---- ISSUE PHASE: all 18 row gathers (each instr fetches 4 rows = 1 KB).
    const f4 ue4 = usr4[(long)ub * 16 + s];
    const f4 ie4 = ent4[(long)vb * 16 + s];
    f4 Re[4], Ag[4], Lu[4], Li[4];
    Re[0] = rel4[iar.x * 16 + s];
    Re[1] = rel4[iar.y * 16 + s];
    Re[2] = rel4[iar.z * 16 + s];
    Re[3] = rel4[iar.w * 16 + s];
    Ag[0] = ent4[(long)iae.x * 16 + s];
    Ag[1] = ent4[(long)iae.y * 16 + s];
    Ag[2] = ent4[(long)iae.z * 16 + s];
    Ag[3] = ent4[(long)iae.w * 16 + s];
    Lu[0] = usr4[(long)iit.x * 16 + s];
    Lu[1] = usr4[(long)iit.y * 16 + s];
    Lu[2] = usr4[(long)iit.z * 16 + s];
    Lu[3] = usr4[(long)iit.w * 16 + s];
    Li[0] = ent4[(long)iun.x * 16 + s];
    Li[1] = ent4[(long)iun.y * 16 + s];
    Li[2] = ent4[(long)iun.z * 16 + s];
    Li[3] = ent4[(long)iun.w * 16 + s];

    // Hard scheduling fence: nothing moves across. All 18 loads are issued
    // before any consumption -> one progressive vmcnt drain, not 16 batches.
    __builtin_amdgcn_sched_barrier(0);

    // ---- CONSUME PHASE (same order as issue: FIFO vmcnt drain).
    // Attention scores: sc[k] = dot(ue, rel_row[4g+k]) (in-group reduce).
    float sc[4];
#pragma unroll
    for (int k = 0; k < 4; k++) {
        float p = dot4(ue4, Re[k]);
        p += __shfl_xor(p, 1, 64); p += __shfl_xor(p, 2, 64);
        p += __shfl_xor(p, 4, 64); p += __shfl_xor(p, 8, 64);
        sc[k] = p;  // identical across the 16 lanes of group g
    }
    float m = fmaxf(fmaxf(sc[0], sc[1]), fmaxf(sc[2], sc[3]));
    m = fmaxf(m, __shfl_xor(m, 16, 64));
    m = fmaxf(m, __shfl_xor(m, 32, 64));
    float e[4];
    float ssum = 0.f;
#pragma unroll
    for (int k = 0; k < 4; k++) { e[k] = __expf(sc[k] - m); ssum += e[k]; }
    ssum += __shfl_xor(ssum, 16, 64);
    ssum += __shfl_xor(ssum, 32, 64);
    const float inv = 1.0f / ssum;

    // neighbors_agg: this lane holds the attn weights for its own rows.
    f4 ag = {0.f, 0.f, 0.f, 0.f};
#pragma unroll
    for (int k = 0; k < 4; k++) {
        ag.x = fmaf(e[k], Ag[k].x, ag.x);
        ag.y = fmaf(e[k], Ag[k].y, ag.y);
        ag.z = fmaf(e[k], Ag[k].z, ag.z);
        ag.w = fmaf(e[k], Ag[k].w, ag.w);
    }
    ag = xgrp_sum(ag);  // sum over all 16 rows; replicated across groups

    f4 comb;
    comb.x = fmaf(ag.x, inv, ie4.x);
    comb.y = fmaf(ag.y, inv, ie4.y);
    comb.z = fmaf(ag.z, inv, ie4.z);
    comb.w = fmaf(ag.w, inv, ie4.w);
    const float cc[4] = {comb.x, comb.y, comb.z, comb.w};

    // lite sums.
    f4 lu;
    lu.x = Lu[0].x + Lu[1].x + Lu[2].x + Lu[3].x;
    lu.y = Lu[0].y + Lu[1].y + Lu[2].y + Lu[3].y;
    lu.z = Lu[0].z + Lu[1].z + Lu[2].z + Lu[3].z;
    lu.w = Lu[0].w + Lu[1].w + Lu[2].w + Lu[3].w;
    lu = xgrp_sum(lu);
    f4 li;
    li.x = Li[0].x + Li[1].x + Li[2].x + Li[3].x;
    li.y = Li[0].y + Li[1].y + Li[2].y + Li[3].y;
    li.z = Li[0].z + Li[1].z + Li[2].z + Li[3].z;
    li.w = Li[0].w + Li[1].w + Li[2].w + Li[3].w;
    li = xgrp_sum(li);

    // 64x64 matvec: lane (g,s) accumulates d in [16g,16g+16) for out-chunk s.
    // comb replicated across groups; chunk 4g+(j>>2) lives in lane 20g+(j>>2).
    f4 acc = {0.f, 0.f, 0.f, 0.f};
#pragma unroll
    for (int j = 0; j < 16; j++) {
        const int d = 16 * g + j;
        const float cd = __shfl(cc[j & 3], 20 * g + (j >> 2), 64);
        const f4 w = W4[d * 16 + s];
        acc.x = fmaf(cd, w.x, acc.x);
        acc.y = fmaf(cd, w.y, acc.y);
        acc.z = fmaf(cd, w.z, acc.z);
        acc.w = fmaf(cd, w.w, acc.w);
    }
    acc = xgrp_sum(acc);
    const f4 bias = b4p[s];
    f4 item4;
    item4.x = tanhf(acc.x + bias.x);
    item4.y = tanhf(acc.y + bias.y);
    item4.z = tanhf(acc.z + bias.z);
    item4.w = tanhf(acc.w + bias.w);

    // final score: dot over 64 dims = in-group reduce over 16 chunks.
    f4 uf, itf;
    uf.x = 0.5f * fmaf(lu.x, 1.f / NNB, ue4.x);
    uf.y = 0.5f * fmaf(lu.y, 1.f / NNB, ue4.y);
    uf.z = 0.5f * fmaf(lu.z, 1.f / NNB, ue4.z);
    uf.w = 0.5f * fmaf(lu.w, 1.f / NNB, ue4.w);
    itf.x = 0.5f * fmaf(li.x, 1.f / NNB, item4.x);
    itf.y = 0.5f * fmaf(li.y, 1.f / NNB, item4.y);
    itf.z = 0.5f * fmaf(li.z, 1.f / NNB, item4.z);
    itf.w = 0.5f * fmaf(li.w, 1.f / NNB, item4.w);

    float p = dot4(uf, itf);
    p += __shfl_xor(p, 1, 64); p += __shfl_xor(p, 2, 64);
    p += __shfl_xor(p, 4, 64); p += __shfl_xor(p, 8, 64);

    if (lane == 0) out[b] = 1.0f / (1.0f + __expf(-p));
}

extern "C" void kernel_launch(void* const* d_in, const int* in_sizes, int n_in,
                              void* d_out, int out_size, void* d_ws, size_t ws_size,
                              hipStream_t stream)
{
    const int*   u             = (const int*)d_in[0];
    const int*   v             = (const int*)d_in[1];
    const int*   user_neighbor = (const int*)d_in[2];
    const int*   item_neighbor = (const int*)d_in[3];
    const int*   adj_ent       = (const int*)d_in[4];
    const int*   adj_rel       = (const int*)d_in[5];
    const float* usr_emb       = (const float*)d_in[6];
    const float* ent_emb       = (const float*)d_in[7];
    const float* rel_emb       = (const float*)d_in[8];
    const float* agg_W         = (const float*)d_in[9];
    const float* agg_b         = (const float*)d_in[10];
    float* out = (float*)d_out;

    constexpr int WPB = 4;  // 4 waves/block, one batch element per wave
    dim3 grid(BATCH / WPB), block(WPB * 64);
    klgcn_kernel<WPB><<<grid, block, 0, stream>>>(
        u, v, user_neighbor, item_neighbor, adj_ent, adj_rel,
        usr_emb, ent_emb, rel_emb, agg_W, agg_b, out);
}